// Round 1
// baseline (3016.753 us; speedup 1.0000x reference)
//
#include <hip/hip_runtime.h>
#include <math.h>
#include <float.h>

#define INPUT_DIM 1024
#define HIDDEN 128
#define BM 64
#define BK 32
#define STRX 36      // x tile row stride (floats), 16B-aligned, bank-spread
#define STRW 260     // W tile row stride (floats), 16B-aligned
#define NTHREADS 256
#define KSEL 10

// ---------------------------------------------------------------------------
// Kernel 1: fused scores = (tanh(x@Wv+bv) * sigmoid(x@Wu+bu)) @ Ww + bw
// One block computes 64 instances x all 256 channels (128 V + 128 U).
// Thread (ty,tx) with ty=tid/16, tx=tid%16 owns 4 instances (rows ty*4+m)
// and 16 channels c = tx*4 + 64*j + ci (j=0,1 -> V ch, j=2,3 -> U ch).
// Also zeroes the atten output slice for its instances.
// ---------------------------------------------------------------------------
__global__ __launch_bounds__(256) void scores_kernel(
    const float* __restrict__ x,
    const float* __restrict__ Wv, const float* __restrict__ bv,
    const float* __restrict__ Wu, const float* __restrict__ bu,
    const float* __restrict__ Ww, const float* __restrict__ bw,
    float* __restrict__ scores, float* __restrict__ atten, int N)
{
    __shared__ float xs[BM * STRX];   // 9216 B
    __shared__ float wsm[BK * STRW];  // 33280 B

    const int tid = threadIdx.x;
    const int tx = tid & 15;
    const int ty = tid >> 4;
    const int b = blockIdx.y;
    const int i0 = blockIdx.x * BM;

    // zero atten slice (kernel 2 scatters into it later on the same stream)
    if (tid < BM && (i0 + tid) < N) atten[(size_t)b * N + i0 + tid] = 0.0f;

    float acc[4][16];
    #pragma unroll
    for (int m = 0; m < 4; ++m)
        #pragma unroll
        for (int c = 0; c < 16; ++c) acc[m][c] = 0.0f;

    const float* xb = x + (size_t)b * N * INPUT_DIM;

    for (int k0 = 0; k0 < INPUT_DIM; k0 += BK) {
        // stage x tile: 64 rows x 32 floats = 512 float4, 2 per thread
        #pragma unroll
        for (int r = 0; r < 2; ++r) {
            int li = tid + r * NTHREADS;    // 0..511
            int row = li >> 3;
            int c4 = li & 7;
            float4 v = make_float4(0.f, 0.f, 0.f, 0.f);
            int gi = i0 + row;
            if (gi < N) v = *(const float4*)(xb + (size_t)gi * INPUT_DIM + k0 + c4 * 4);
            *(float4*)(&xs[row * STRX + c4 * 4]) = v;
        }
        // stage W tiles: Wv rows -> cols 0..127, Wu rows -> cols 128..255
        #pragma unroll
        for (int r = 0; r < 4; ++r) {
            int li = tid + r * NTHREADS;    // 0..1023
            int kk = li >> 5;               // 0..31
            int c4 = li & 31;               // 0..31  -> col c4*4
            float4 v = *(const float4*)(Wv + (size_t)(k0 + kk) * HIDDEN + c4 * 4);
            *(float4*)(&wsm[kk * STRW + c4 * 4]) = v;
            float4 u = *(const float4*)(Wu + (size_t)(k0 + kk) * HIDDEN + c4 * 4);
            *(float4*)(&wsm[kk * STRW + 128 + c4 * 4]) = u;
        }
        __syncthreads();

        #pragma unroll
        for (int kk4 = 0; kk4 < BK / 4; ++kk4) {
            float xr[4][4];
            #pragma unroll
            for (int m = 0; m < 4; ++m) {
                float4 v = *(const float4*)(&xs[(ty * 4 + m) * STRX + kk4 * 4]);
                xr[m][0] = v.x; xr[m][1] = v.y; xr[m][2] = v.z; xr[m][3] = v.w;
            }
            #pragma unroll
            for (int q = 0; q < 4; ++q) {
                float wv[16];
                #pragma unroll
                for (int j = 0; j < 4; ++j) {
                    float4 v = *(const float4*)(&wsm[(kk4 * 4 + q) * STRW + j * 64 + tx * 4]);
                    wv[j*4+0] = v.x; wv[j*4+1] = v.y; wv[j*4+2] = v.z; wv[j*4+3] = v.w;
                }
                #pragma unroll
                for (int m = 0; m < 4; ++m) {
                    float xq = xr[m][q];
                    #pragma unroll
                    for (int c = 0; c < 16; ++c)
                        acc[m][c] = fmaf(xq, wv[c], acc[m][c]);
                }
            }
        }
        __syncthreads();
    }

    // epilogue: bias + activations + per-channel weight, then reduce over tx
    float bvv[8], buu[8], www[8];
    #pragma unroll
    for (int j = 0; j < 2; ++j)
        #pragma unroll
        for (int ci = 0; ci < 4; ++ci) {
            int ch = tx * 4 + 64 * j + ci;
            bvv[j*4+ci] = bv[ch];
            buu[j*4+ci] = bu[ch];
            www[j*4+ci] = Ww[ch];
        }
    float bw0 = bw[0];

    #pragma unroll
    for (int m = 0; m < 4; ++m) {
        float part = 0.f;
        #pragma unroll
        for (int j = 0; j < 2; ++j)
            #pragma unroll
            for (int ci = 0; ci < 4; ++ci) {
                float v = tanhf(acc[m][j*4+ci] + bvv[j*4+ci]);
                float uarg = acc[m][(j+2)*4+ci] + buu[j*4+ci];
                float u = 1.0f / (1.0f + expf(-uarg));
                part = fmaf(v * u, www[j*4+ci], part);
            }
        // reduce across the 16 tx lanes (same ty group within the wave)
        #pragma unroll
        for (int off = 1; off < 16; off <<= 1)
            part += __shfl_xor(part, off, 64);
        int gi = i0 + ty * 4 + m;
        if (tx == 0 && gi < N)
            scores[(size_t)b * N + gi] = part + bw0;
    }
}

// ---------------------------------------------------------------------------
// Kernel 2: per bag, select top-10 and bottom-10 scores, softmax over the 20,
// scatter weights into atten, store (idx, w) lists for the Z gather.
// One block per bag, 256 threads.
// ---------------------------------------------------------------------------
__global__ __launch_bounds__(256) void select_kernel(
    const float* __restrict__ scores, float* __restrict__ atten,
    int* __restrict__ sel_idx, float* __restrict__ sel_w, int N)
{
    const int b = blockIdx.x;
    const int tid = threadIdx.x;
    const float* s = scores + (size_t)b * N;

    // per-thread top-10 (descending) and bottom-10 (ascending), in registers
    float tv[KSEL]; int ti[KSEL];
    float lv[KSEL]; int li[KSEL];
    #pragma unroll
    for (int j = 0; j < KSEL; ++j) { tv[j] = -FLT_MAX; ti[j] = -1; lv[j] = FLT_MAX; li[j] = -1; }

    for (int i = tid; i < N; i += NTHREADS) {
        float v = s[i];
        if (v > tv[KSEL-1]) {
            #pragma unroll
            for (int j = KSEL-1; j >= 1; --j) {
                if (v > tv[j-1])      { tv[j] = tv[j-1]; ti[j] = ti[j-1]; }
                else if (v > tv[j])   { tv[j] = v;       ti[j] = i;       }
            }
            if (v > tv[0]) { tv[0] = v; ti[0] = i; }
        }
        if (v < lv[KSEL-1]) {
            #pragma unroll
            for (int j = KSEL-1; j >= 1; --j) {
                if (v < lv[j-1])      { lv[j] = lv[j-1]; li[j] = li[j-1]; }
                else if (v < lv[j])   { lv[j] = v;       li[j] = i;       }
            }
            if (v < lv[0]) { lv[0] = v; li[0] = i; }
        }
    }

    __shared__ float rv[4]; __shared__ int rw[4];
    __shared__ int winner;
    __shared__ float selv[2*KSEL]; __shared__ int seli[2*KSEL];

    // merge top-10 across threads: 10 rounds of block argmax of each thread's head
    for (int r = 0; r < KSEL; ++r) {
        float v = tv[0];
        int who = tid;
        #pragma unroll
        for (int off = 32; off > 0; off >>= 1) {
            float ov = __shfl_down(v, off, 64);
            int ow = __shfl_down(who, off, 64);
            if (ov > v) { v = ov; who = ow; }
        }
        if ((tid & 63) == 0) { rv[tid >> 6] = v; rw[tid >> 6] = who; }
        __syncthreads();
        if (tid == 0) {
            float bv2 = rv[0]; int bw2 = rw[0];
            for (int w2 = 1; w2 < 4; ++w2) if (rv[w2] > bv2) { bv2 = rv[w2]; bw2 = rw[w2]; }
            winner = bw2;
        }
        __syncthreads();
        if (tid == winner) {
            selv[r] = tv[0]; seli[r] = ti[0];
            #pragma unroll
            for (int j = 0; j < KSEL-1; ++j) { tv[j] = tv[j+1]; ti[j] = ti[j+1]; }
            tv[KSEL-1] = -FLT_MAX;
        }
        __syncthreads();
    }
    // merge bottom-10
    for (int r = 0; r < KSEL; ++r) {
        float v = lv[0];
        int who = tid;
        #pragma unroll
        for (int off = 32; off > 0; off >>= 1) {
            float ov = __shfl_down(v, off, 64);
            int ow = __shfl_down(who, off, 64);
            if (ov < v) { v = ov; who = ow; }
        }
        if ((tid & 63) == 0) { rv[tid >> 6] = v; rw[tid >> 6] = who; }
        __syncthreads();
        if (tid == 0) {
            float bv2 = rv[0]; int bw2 = rw[0];
            for (int w2 = 1; w2 < 4; ++w2) if (rv[w2] < bv2) { bv2 = rv[w2]; bw2 = rw[w2]; }
            winner = bw2;
        }
        __syncthreads();
        if (tid == winner) {
            selv[KSEL + r] = lv[0]; seli[KSEL + r] = li[0];
            #pragma unroll
            for (int j = 0; j < KSEL-1; ++j) { lv[j] = lv[j+1]; li[j] = li[j+1]; }
            lv[KSEL-1] = FLT_MAX;
        }
        __syncthreads();
    }

    // softmax over the 20 selected, scatter into atten, store lists
    if (tid == 0) {
        float m = -FLT_MAX;
        #pragma unroll
        for (int j = 0; j < 2*KSEL; ++j) m = fmaxf(m, selv[j]);
        float e[2*KSEL]; float sum = 0.f;
        #pragma unroll
        for (int j = 0; j < 2*KSEL; ++j) { e[j] = expf(selv[j] - m); sum += e[j]; }
        float inv = 1.0f / sum;
        #pragma unroll
        for (int j = 0; j < 2*KSEL; ++j) {
            float w = e[j] * inv;
            atten[(size_t)b * N + seli[j]] = w;
            sel_idx[b * 2 * KSEL + j] = seli[j];
            sel_w[b * 2 * KSEL + j] = w;
        }
    }
}

// ---------------------------------------------------------------------------
// Kernel 3: Z[b,:] = sum_j w_j * x[b, idx_j, :]. One block per bag.
// ---------------------------------------------------------------------------
__global__ __launch_bounds__(256) void z_kernel(
    const float* __restrict__ x, const int* __restrict__ sel_idx,
    const float* __restrict__ sel_w, float* __restrict__ Z, int N)
{
    const int b = blockIdx.x;
    const int tid = threadIdx.x;   // 256 threads * float4 = 1024 floats
    float4 acc = make_float4(0.f, 0.f, 0.f, 0.f);
    #pragma unroll
    for (int j = 0; j < 2*KSEL; ++j) {
        int idx = sel_idx[b * 2 * KSEL + j];
        float w = sel_w[b * 2 * KSEL + j];
        const float4* xr = (const float4*)(x + ((size_t)b * N + idx) * INPUT_DIM);
        float4 v = xr[tid];
        acc.x = fmaf(w, v.x, acc.x);
        acc.y = fmaf(w, v.y, acc.y);
        acc.z = fmaf(w, v.z, acc.z);
        acc.w = fmaf(w, v.w, acc.w);
    }
    ((float4*)(Z + (size_t)b * INPUT_DIM))[tid] = acc;
}

extern "C" void kernel_launch(void* const* d_in, const int* in_sizes, int n_in,
                              void* d_out, int out_size, void* d_ws, size_t ws_size,
                              hipStream_t stream)
{
    const float* x  = (const float*)d_in[0];
    const float* Wv = (const float*)d_in[1];
    const float* bv = (const float*)d_in[2];
    const float* Wu = (const float*)d_in[3];
    const float* bu = (const float*)d_in[4];
    const float* Ww = (const float*)d_in[5];
    const float* bw = (const float*)d_in[6];

    const int B = 8;
    const int N = in_sizes[0] / (B * INPUT_DIM);   // 50000

    float* Z = (float*)d_out;                              // [B,1024]
    float* atten = (float*)d_out + (size_t)B * INPUT_DIM;  // [B,N]

    // workspace layout
    float* scores = (float*)d_ws;                                          // B*N floats
    char* p = (char*)d_ws + (size_t)B * N * sizeof(float);
    int* sel_idx = (int*)p;                                                // B*20 ints
    float* sel_w = (float*)(p + (size_t)B * 2 * KSEL * sizeof(int));       // B*20 floats

    dim3 g1((N + BM - 1) / BM, B);
    scores_kernel<<<g1, NTHREADS, 0, stream>>>(x, Wv, bv, Wu, bu, Ww, bw, scores, atten, N);
    select_kernel<<<B, NTHREADS, 0, stream>>>(scores, atten, sel_idx, sel_w, N);
    z_kernel<<<B, NTHREADS, 0, stream>>>(x, sel_idx, sel_w, Z, N);
}

// Round 2
// 1344.899 us; speedup vs baseline: 2.2431x; 2.2431x over previous
//
#include <hip/hip_runtime.h>
#include <math.h>
#include <float.h>

#define INPUT_DIM 1024
#define HIDDEN 128
#define NTHREADS 256
#define KSEL 10

// scores kernel geometry
#define BM 128        // rows per block
#define BK 64         // k per LDS tile
#define SCORE_THREADS 512   // 8 waves: 2 wave-rows x 4 wave-cols

typedef short short8 __attribute__((ext_vector_type(8)));
typedef float f32x4 __attribute__((ext_vector_type(4)));

static __device__ __forceinline__ unsigned short f2bf(float f) {
    union { float f; unsigned u; } v; v.f = f;
    unsigned r = v.u + 0x7FFF + ((v.u >> 16) & 1);   // RNE
    return (unsigned short)(r >> 16);
}
static __device__ __forceinline__ float bf2f(unsigned short h) {
    union { unsigned u; float f; } v; v.u = ((unsigned)h) << 16;
    return v.f;
}
static __device__ __forceinline__ float fast_tanh(float a) {
    float e = __expf(2.0f * a);
    return 1.0f - 2.0f / (e + 1.0f);
}
static __device__ __forceinline__ float fast_sigmoid(float a) {
    return 1.0f / (1.0f + __expf(-a));
}

// ---------------------------------------------------------------------------
// Repack W into MFMA B-fragment order, split into bf16 hi/lo.
// Packed col pc (0..255): pc = 2h + (0 for Wv, 1 for Wu), h = hidden channel.
// Layout: wp[kg][cg][lane][e], kg=k/32 (32), cg=pc/16 (16), lane 0..63, e 0..7
//   where k = kg*32 + (lane>>4)*8 + e, pc = cg*16 + (lane&15).
// grid 512 blocks x 64 threads.
// ---------------------------------------------------------------------------
__global__ __launch_bounds__(64) void repack_kernel(
    const float* __restrict__ Wv, const float* __restrict__ Wu,
    unsigned short* __restrict__ wp_hi, unsigned short* __restrict__ wp_lo)
{
    int bid = blockIdx.x;           // kg*16 + cg
    int l = threadIdx.x;
    int pc = (bid & 15) * 16 + (l & 15);
    int h = pc >> 1;
    const float* src = (pc & 1) ? Wu : Wv;
    int kbase = (bid >> 4) * 32 + (l >> 4) * 8;
    size_t off = ((size_t)bid * 64 + l) * 8;
    #pragma unroll
    for (int e = 0; e < 8; ++e) {
        float w = src[(size_t)(kbase + e) * HIDDEN + h];
        unsigned short hi = f2bf(w);
        unsigned short lo = f2bf(w - bf2f(hi));
        wp_hi[off + e] = hi;
        wp_lo[off + e] = lo;
    }
}

// ---------------------------------------------------------------------------
// Kernel 1: fused scores via split-bf16 MFMA.
// Block: 512 thr = 8 waves (2 wave-rows x 4 wave-cols), tile 128 rows x 256 pc.
// Wave (wr,wc): rows wr*64 + m*16, packed cols wc*64 + n*16 (m,n = 0..3).
// ---------------------------------------------------------------------------
__global__ __launch_bounds__(512) void scores_kernel(
    const float* __restrict__ x,
    const unsigned short* __restrict__ wp_hi, const unsigned short* __restrict__ wp_lo,
    const float* __restrict__ bv, const float* __restrict__ bu,
    const float* __restrict__ Ww, const float* __restrict__ bw,
    float* __restrict__ scores, float* __restrict__ atten, int N)
{
    __shared__ unsigned short As_hi[BM * BK];   // 16 KB, XOR-swizzled
    __shared__ unsigned short As_lo[BM * BK];   // 16 KB
    __shared__ float partial[4][BM];            // 2 KB

    const int tid = threadIdx.x;
    const int l = tid & 63;
    const int wid = tid >> 6;
    const int wr = wid >> 2;       // 0..1
    const int wc = wid & 3;        // 0..3
    const int b = blockIdx.y;
    const int i0 = blockIdx.x * BM;
    const float* xb = x + (size_t)b * N * INPUT_DIM;

    f32x4 acc[4][4];
    #pragma unroll
    for (int m = 0; m < 4; ++m)
        #pragma unroll
        for (int n = 0; n < 4; ++n)
            acc[m][n] = (f32x4){0.f, 0.f, 0.f, 0.f};

    for (int kt = 0; kt < INPUT_DIM / BK; ++kt) {
        const int k0 = kt * BK;
        // ---- stage x tile (fp32 -> bf16 hi/lo), swizzled LDS write ----
        #pragma unroll
        for (int r = 0; r < 4; ++r) {
            int li = tid + r * SCORE_THREADS;   // 0..2047
            int row = li >> 4;                  // 0..127
            int c4 = li & 15;                   // float4 index within row
            int gi = i0 + row;
            float4 v = make_float4(0.f, 0.f, 0.f, 0.f);
            if (gi < N) v = *(const float4*)(xb + (size_t)gi * INPUT_DIM + k0 + c4 * 4);
            unsigned short h0 = f2bf(v.x), h1 = f2bf(v.y), h2 = f2bf(v.z), h3 = f2bf(v.w);
            unsigned short l0 = f2bf(v.x - bf2f(h0)), l1 = f2bf(v.y - bf2f(h1));
            unsigned short l2 = f2bf(v.z - bf2f(h2)), l3 = f2bf(v.w - bf2f(h3));
            int idx = (row * BK + c4 * 4) ^ ((row & 7) << 3);   // ushort units
            *(uint2*)(&As_hi[idx]) = make_uint2((unsigned)h0 | ((unsigned)h1 << 16),
                                                (unsigned)h2 | ((unsigned)h3 << 16));
            *(uint2*)(&As_lo[idx]) = make_uint2((unsigned)l0 | ((unsigned)l1 << 16),
                                                (unsigned)l2 | ((unsigned)l3 << 16));
        }
        __syncthreads();

        #pragma unroll
        for (int ks = 0; ks < BK / 32; ++ks) {
            const int kg = (k0 >> 5) + ks;
            // B fragments from packed global (L2-resident)
            short8 bh[4], bl[4];
            #pragma unroll
            for (int n = 0; n < 4; ++n) {
                int cg = wc * 4 + n;
                size_t off = ((size_t)(kg * 16 + cg) * 64 + l) * 8;
                bh[n] = *(const short8*)(wp_hi + off);
                bl[n] = *(const short8*)(wp_lo + off);
            }
            // A fragments from LDS
            short8 ah[4], al[4];
            #pragma unroll
            for (int m = 0; m < 4; ++m) {
                int row = wr * 64 + m * 16 + (l & 15);
                int k = ks * 32 + (l >> 4) * 8;
                int idx = (row * BK + k) ^ ((row & 7) << 3);
                ah[m] = *(const short8*)(&As_hi[idx]);
                al[m] = *(const short8*)(&As_lo[idx]);
            }
            // 3-term split MFMA
            #pragma unroll
            for (int m = 0; m < 4; ++m)
                #pragma unroll
                for (int n = 0; n < 4; ++n) {
                    acc[m][n] = __builtin_amdgcn_mfma_f32_16x16x32_bf16(ah[m], bh[n], acc[m][n], 0, 0, 0);
                    acc[m][n] = __builtin_amdgcn_mfma_f32_16x16x32_bf16(al[m], bh[n], acc[m][n], 0, 0, 0);
                    acc[m][n] = __builtin_amdgcn_mfma_f32_16x16x32_bf16(ah[m], bl[n], acc[m][n], 0, 0, 0);
                }
        }
        __syncthreads();
    }

    // ---- epilogue: gate, project, row-reduce ----
    // lane's packed col within frag n: pc = wc*64 + n*16 + (l&15); h = pc>>1
    float bvv[4], buu[4], www[4];
    #pragma unroll
    for (int n = 0; n < 4; ++n) {
        int h = (wc * 64 + n * 16 + (l & 15)) >> 1;
        bvv[n] = bv[h]; buu[n] = bu[h]; www[n] = Ww[h];
    }
    const bool isV = ((l & 1) == 0);

    #pragma unroll
    for (int m = 0; m < 4; ++m) {
        float cs[4] = {0.f, 0.f, 0.f, 0.f};
        #pragma unroll
        for (int n = 0; n < 4; ++n) {
            #pragma unroll
            for (int r = 0; r < 4; ++r) {
                float v = acc[m][n][r];
                float u = __shfl_xor(v, 1, 64);    // partner col's pre-activation
                float g = 0.f;
                if (isV)
                    g = fast_tanh(v + bvv[n]) * fast_sigmoid(u + buu[n]) * www[n];
                cs[r] += g;
            }
        }
        // reduce across the 16 lanes of the group (cols of this wave's slab)
        #pragma unroll
        for (int r = 0; r < 4; ++r) {
            #pragma unroll
            for (int off = 1; off < 16; off <<= 1)
                cs[r] += __shfl_xor(cs[r], off, 64);
        }
        if ((l & 15) == 0) {
            #pragma unroll
            for (int r = 0; r < 4; ++r)
                partial[wc][wr * 64 + m * 16 + (l >> 4) * 4 + r] = cs[r];
        }
    }
    __syncthreads();

    if (tid < BM) {
        int gi = i0 + tid;
        if (gi < N) {
            float s = partial[0][tid] + partial[1][tid] + partial[2][tid] + partial[3][tid] + bw[0];
            scores[(size_t)b * N + gi] = s;
            atten[(size_t)b * N + gi] = 0.0f;
        }
    }
}

// ---------------------------------------------------------------------------
// Kernel 2: per bag top-10 / bottom-10, softmax over 20, scatter into atten.
// ---------------------------------------------------------------------------
__global__ __launch_bounds__(256) void select_kernel(
    const float* __restrict__ scores, float* __restrict__ atten,
    int* __restrict__ sel_idx, float* __restrict__ sel_w, int N)
{
    const int b = blockIdx.x;
    const int tid = threadIdx.x;
    const float* s = scores + (size_t)b * N;

    float tv[KSEL]; int ti[KSEL];
    float lv[KSEL]; int li[KSEL];
    #pragma unroll
    for (int j = 0; j < KSEL; ++j) { tv[j] = -FLT_MAX; ti[j] = -1; lv[j] = FLT_MAX; li[j] = -1; }

    for (int i = tid; i < N; i += NTHREADS) {
        float v = s[i];
        if (v > tv[KSEL-1]) {
            #pragma unroll
            for (int j = KSEL-1; j >= 1; --j) {
                if (v > tv[j-1])      { tv[j] = tv[j-1]; ti[j] = ti[j-1]; }
                else if (v > tv[j])   { tv[j] = v;       ti[j] = i;       }
            }
            if (v > tv[0]) { tv[0] = v; ti[0] = i; }
        }
        if (v < lv[KSEL-1]) {
            #pragma unroll
            for (int j = KSEL-1; j >= 1; --j) {
                if (v < lv[j-1])      { lv[j] = lv[j-1]; li[j] = li[j-1]; }
                else if (v < lv[j])   { lv[j] = v;       li[j] = i;       }
            }
            if (v < lv[0]) { lv[0] = v; li[0] = i; }
        }
    }

    __shared__ float rv[4]; __shared__ int rw[4];
    __shared__ int winner;
    __shared__ float selv[2*KSEL]; __shared__ int seli[2*KSEL];

    for (int r = 0; r < KSEL; ++r) {
        float v = tv[0];
        int who = tid;
        #pragma unroll
        for (int off = 32; off > 0; off >>= 1) {
            float ov = __shfl_down(v, off, 64);
            int ow = __shfl_down(who, off, 64);
            if (ov > v) { v = ov; who = ow; }
        }
        if ((tid & 63) == 0) { rv[tid >> 6] = v; rw[tid >> 6] = who; }
        __syncthreads();
        if (tid == 0) {
            float bv2 = rv[0]; int bw2 = rw[0];
            for (int w2 = 1; w2 < 4; ++w2) if (rv[w2] > bv2) { bv2 = rv[w2]; bw2 = rw[w2]; }
            winner = bw2;
        }
        __syncthreads();
        if (tid == winner) {
            selv[r] = tv[0]; seli[r] = ti[0];
            #pragma unroll
            for (int j = 0; j < KSEL-1; ++j) { tv[j] = tv[j+1]; ti[j] = ti[j+1]; }
            tv[KSEL-1] = -FLT_MAX;
        }
        __syncthreads();
    }
    for (int r = 0; r < KSEL; ++r) {
        float v = lv[0];
        int who = tid;
        #pragma unroll
        for (int off = 32; off > 0; off >>= 1) {
            float ov = __shfl_down(v, off, 64);
            int ow = __shfl_down(who, off, 64);
            if (ov < v) { v = ov; who = ow; }
        }
        if ((tid & 63) == 0) { rv[tid >> 6] = v; rw[tid >> 6] = who; }
        __syncthreads();
        if (tid == 0) {
            float bv2 = rv[0]; int bw2 = rw[0];
            for (int w2 = 1; w2 < 4; ++w2) if (rv[w2] < bv2) { bv2 = rv[w2]; bw2 = rw[w2]; }
            winner = bw2;
        }
        __syncthreads();
        if (tid == winner) {
            selv[KSEL + r] = lv[0]; seli[KSEL + r] = li[0];
            #pragma unroll
            for (int j = 0; j < KSEL-1; ++j) { lv[j] = lv[j+1]; li[j] = li[j+1]; }
            lv[KSEL-1] = FLT_MAX;
        }
        __syncthreads();
    }

    if (tid == 0) {
        float m = -FLT_MAX;
        #pragma unroll
        for (int j = 0; j < 2*KSEL; ++j) m = fmaxf(m, selv[j]);
        float e[2*KSEL]; float sum = 0.f;
        #pragma unroll
        for (int j = 0; j < 2*KSEL; ++j) { e[j] = expf(selv[j] - m); sum += e[j]; }
        float inv = 1.0f / sum;
        #pragma unroll
        for (int j = 0; j < 2*KSEL; ++j) {
            float w = e[j] * inv;
            atten[(size_t)b * N + seli[j]] = w;
            sel_idx[b * 2 * KSEL + j] = seli[j];
            sel_w[b * 2 * KSEL + j] = w;
        }
    }
}

// ---------------------------------------------------------------------------
// Kernel 3: Z[b,:] = sum_j w_j * x[b, idx_j, :]
// ---------------------------------------------------------------------------
__global__ __launch_bounds__(256) void z_kernel(
    const float* __restrict__ x, const int* __restrict__ sel_idx,
    const float* __restrict__ sel_w, float* __restrict__ Z, int N)
{
    const int b = blockIdx.x;
    const int tid = threadIdx.x;
    float4 acc = make_float4(0.f, 0.f, 0.f, 0.f);
    #pragma unroll
    for (int j = 0; j < 2*KSEL; ++j) {
        int idx = sel_idx[b * 2 * KSEL + j];
        float w = sel_w[b * 2 * KSEL + j];
        const float4* xr = (const float4*)(x + ((size_t)b * N + idx) * INPUT_DIM);
        float4 v = xr[tid];
        acc.x = fmaf(w, v.x, acc.x);
        acc.y = fmaf(w, v.y, acc.y);
        acc.z = fmaf(w, v.z, acc.z);
        acc.w = fmaf(w, v.w, acc.w);
    }
    ((float4*)(Z + (size_t)b * INPUT_DIM))[tid] = acc;
}

extern "C" void kernel_launch(void* const* d_in, const int* in_sizes, int n_in,
                              void* d_out, int out_size, void* d_ws, size_t ws_size,
                              hipStream_t stream)
{
    const float* x  = (const float*)d_in[0];
    const float* Wv = (const float*)d_in[1];
    const float* bv = (const float*)d_in[2];
    const float* Wu = (const float*)d_in[3];
    const float* bu = (const float*)d_in[4];
    const float* Ww = (const float*)d_in[5];
    const float* bw = (const float*)d_in[6];

    const int B = 8;
    const int N = in_sizes[0] / (B * INPUT_DIM);   // 50000

    float* Z = (float*)d_out;                              // [B,1024]
    float* atten = (float*)d_out + (size_t)B * INPUT_DIM;  // [B,N]

    // workspace layout
    char* p = (char*)d_ws;
    float* scores = (float*)p;                 p += (size_t)B * N * sizeof(float);
    int* sel_idx = (int*)p;                    p += (size_t)B * 2 * KSEL * sizeof(int);
    float* sel_w = (float*)p;                  p += (size_t)B * 2 * KSEL * sizeof(float);
    unsigned short* wp_hi = (unsigned short*)p; p += (size_t)INPUT_DIM * 256 * sizeof(unsigned short);
    unsigned short* wp_lo = (unsigned short*)p;

    repack_kernel<<<512, 64, 0, stream>>>(Wv, Wu, wp_hi, wp_lo);

    dim3 g1((N + BM - 1) / BM, B);
    scores_kernel<<<g1, SCORE_THREADS, 0, stream>>>(x, wp_hi, wp_lo, bv, bu, Ww, bw, scores, atten, N);
    select_kernel<<<B, NTHREADS, 0, stream>>>(scores, atten, sel_idx, sel_w, N);
    z_kernel<<<B, NTHREADS, 0, stream>>>(x, sel_idx, sel_w, Z, N);
}

// Round 3
// 996.134 us; speedup vs baseline: 3.0285x; 1.3501x over previous
//
#include <hip/hip_runtime.h>
#include <math.h>
#include <float.h>

#define INPUT_DIM 1024
#define HIDDEN 128
#define KSEL 10

// scores kernel geometry: 4 waves (1 wave-row x 4 wave-cols), 64x256 tile
#define BM 64
#define BK 64
#define KT (INPUT_DIM / BK)   // 16
#define STH 256
#define NSEL1 32              // stage-1 chunks per bag

typedef short short8 __attribute__((ext_vector_type(8)));
typedef float f32x4 __attribute__((ext_vector_type(4)));

static __device__ __forceinline__ unsigned short f2bf(float f) {
    union { float f; unsigned u; } v; v.f = f;
    unsigned r = v.u + 0x7FFF + ((v.u >> 16) & 1);   // RNE
    return (unsigned short)(r >> 16);
}
static __device__ __forceinline__ float bf2f(unsigned short h) {
    union { unsigned u; float f; } v; v.u = ((unsigned)h) << 16;
    return v.f;
}
// split (a,b) -> packed hi word (truncation) + packed lo word (RNE of residual)
static __device__ __forceinline__ void split2(float a, float b, unsigned& hw, unsigned& lw) {
    unsigned ua = __float_as_uint(a) & 0xFFFF0000u;
    unsigned ub = __float_as_uint(b) & 0xFFFF0000u;
    float ra = a - __uint_as_float(ua);
    float rb = b - __uint_as_float(ub);
    asm("v_perm_b32 %0, %1, %2, %3" : "=v"(hw) : "v"(ub), "v"(ua), "s"(0x07060302));
    asm("v_cvt_pk_bf16_f32 %0, %1, %2" : "=v"(lw) : "v"(ra), "v"(rb));
}
static __device__ __forceinline__ float fast_tanh(float a) {
    float e = __expf(2.0f * a);
    return 1.0f - 2.0f / (e + 1.0f);
}
static __device__ __forceinline__ float fast_sigmoid(float a) {
    return 1.0f / (1.0f + __expf(-a));
}

// ---------------------------------------------------------------------------
// Repack W into MFMA B-fragment order, split into bf16 hi/lo (RNE both).
// pc = 2h + (0 Wv, 1 Wu). wp[kg][cg][lane][e]: k = kg*32+(lane>>4)*8+e,
// pc = cg*16+(lane&15). grid 512 x 64.
// ---------------------------------------------------------------------------
__global__ __launch_bounds__(64) void repack_kernel(
    const float* __restrict__ Wv, const float* __restrict__ Wu,
    unsigned short* __restrict__ wp_hi, unsigned short* __restrict__ wp_lo)
{
    int bid = blockIdx.x;           // kg*16 + cg
    int l = threadIdx.x;
    int pc = (bid & 15) * 16 + (l & 15);
    int h = pc >> 1;
    const float* src = (pc & 1) ? Wu : Wv;
    int kbase = (bid >> 4) * 32 + (l >> 4) * 8;
    size_t off = ((size_t)bid * 64 + l) * 8;
    #pragma unroll
    for (int e = 0; e < 8; ++e) {
        float w = src[(size_t)(kbase + e) * HIDDEN + h];
        unsigned short hi = f2bf(w);
        unsigned short lo = f2bf(w - bf2f(hi));
        wp_hi[off + e] = hi;
        wp_lo[off + e] = lo;
    }
}

// ---------------------------------------------------------------------------
// Kernel 1: fused scores via split-bf16 3-term MFMA.
// 256 thr = 4 waves, each wave: 64 rows x 64 packed cols (4x4 16x16 frags).
// Reg-prefetch next x tile across the barrier; trunc/cvt_pk cheap converts.
// ---------------------------------------------------------------------------
__global__ __launch_bounds__(STH, 3) void scores_kernel(
    const float* __restrict__ x,
    const unsigned short* __restrict__ wp_hi, const unsigned short* __restrict__ wp_lo,
    const float* __restrict__ bv, const float* __restrict__ bu,
    const float* __restrict__ Ww, const float* __restrict__ bw,
    float* __restrict__ scores, float* __restrict__ atten, int N)
{
    __shared__ unsigned short As_hi[BM * BK];   // 8 KB, XOR-swizzled
    __shared__ unsigned short As_lo[BM * BK];   // 8 KB
    __shared__ float partial[4][BM];            // 1 KB

    const int tid = threadIdx.x;
    const int l = tid & 63;
    const int wc = tid >> 6;       // 0..3
    const int b = blockIdx.y;
    const int i0 = blockIdx.x * BM;
    const float* xb = x + (size_t)b * N * INPUT_DIM;

    const int srow = tid >> 4;      // staging row (0..63... wait 256 thr -> rows 0..15 per r)
    const int sc4 = tid & 15;       // staging float4 col

    f32x4 acc[4][4];
    #pragma unroll
    for (int m = 0; m < 4; ++m)
        #pragma unroll
        for (int n = 0; n < 4; ++n)
            acc[m][n] = (f32x4){0.f, 0.f, 0.f, 0.f};

    // prefetch tile 0: rows srow + r*16
    float4 pf[4];
    #pragma unroll
    for (int r = 0; r < 4; ++r) {
        int gi = i0 + srow + r * 16;
        pf[r] = (gi < N) ? *(const float4*)(xb + (size_t)gi * INPUT_DIM + sc4 * 4)
                         : make_float4(0.f, 0.f, 0.f, 0.f);
    }

    for (int kt = 0; kt < KT; ++kt) {
        // ---- convert prefetched tile + write LDS (swizzled) ----
        #pragma unroll
        for (int r = 0; r < 4; ++r) {
            int row = srow + r * 16;
            unsigned hw0, lw0, hw1, lw1;
            split2(pf[r].x, pf[r].y, hw0, lw0);
            split2(pf[r].z, pf[r].w, hw1, lw1);
            int idx = (row * BK + sc4 * 4) ^ ((row & 7) << 3);
            *(uint2*)(&As_hi[idx]) = make_uint2(hw0, hw1);
            *(uint2*)(&As_lo[idx]) = make_uint2(lw0, lw1);
        }
        __syncthreads();

        // ---- issue next-tile global loads (land during MFMA phase) ----
        if (kt + 1 < KT) {
            int k0n = (kt + 1) * BK;
            #pragma unroll
            for (int r = 0; r < 4; ++r) {
                int gi = i0 + srow + r * 16;
                pf[r] = (gi < N) ? *(const float4*)(xb + (size_t)gi * INPUT_DIM + k0n + sc4 * 4)
                                 : make_float4(0.f, 0.f, 0.f, 0.f);
            }
        }

        // ---- MFMA phase ----
        #pragma unroll
        for (int ks = 0; ks < 2; ++ks) {
            const int kg = kt * 2 + ks;
            short8 bh[4], bl[4];
            #pragma unroll
            for (int n = 0; n < 4; ++n) {
                size_t off = ((size_t)(kg * 16 + wc * 4 + n) * 64 + l) * 8;
                bh[n] = *(const short8*)(wp_hi + off);
                bl[n] = *(const short8*)(wp_lo + off);
            }
            #pragma unroll
            for (int m = 0; m < 4; ++m) {
                int row = m * 16 + (l & 15);
                int k = ks * 32 + (l >> 4) * 8;
                int idx = (row * BK + k) ^ ((row & 7) << 3);
                short8 ah = *(const short8*)(&As_hi[idx]);
                short8 al = *(const short8*)(&As_lo[idx]);
                #pragma unroll
                for (int n = 0; n < 4; ++n) {
                    acc[m][n] = __builtin_amdgcn_mfma_f32_16x16x32_bf16(ah, bh[n], acc[m][n], 0, 0, 0);
                    acc[m][n] = __builtin_amdgcn_mfma_f32_16x16x32_bf16(al, bh[n], acc[m][n], 0, 0, 0);
                    acc[m][n] = __builtin_amdgcn_mfma_f32_16x16x32_bf16(ah, bl[n], acc[m][n], 0, 0, 0);
                }
            }
        }
        __syncthreads();
    }

    // ---- epilogue: gate, project, row-reduce ----
    float bvv[4], buu[4], www[4];
    #pragma unroll
    for (int n = 0; n < 4; ++n) {
        int h = (wc * 64 + n * 16 + (l & 15)) >> 1;
        bvv[n] = bv[h]; buu[n] = bu[h]; www[n] = Ww[h];
    }
    const bool isV = ((l & 1) == 0);

    #pragma unroll
    for (int m = 0; m < 4; ++m) {
        float cs[4] = {0.f, 0.f, 0.f, 0.f};
        #pragma unroll
        for (int n = 0; n < 4; ++n) {
            #pragma unroll
            for (int r = 0; r < 4; ++r) {
                float v = acc[m][n][r];
                float u = __shfl_xor(v, 1, 64);     // partner col (U pre-act)
                if (isV)
                    cs[r] += fast_tanh(v + bvv[n]) * fast_sigmoid(u + buu[n]) * www[n];
            }
        }
        #pragma unroll
        for (int r = 0; r < 4; ++r) {
            #pragma unroll
            for (int off = 1; off < 16; off <<= 1)
                cs[r] += __shfl_xor(cs[r], off, 64);
        }
        if ((l & 15) == 0) {
            #pragma unroll
            for (int r = 0; r < 4; ++r)
                partial[wc][m * 16 + (l >> 4) * 4 + r] = cs[r];
        }
    }
    __syncthreads();

    if (tid < BM) {
        int gi = i0 + tid;
        if (gi < N) {
            float s = partial[0][tid] + partial[1][tid] + partial[2][tid] + partial[3][tid] + bw[0];
            scores[(size_t)b * N + gi] = s;
            atten[(size_t)b * N + gi] = 0.0f;
        }
    }
}

// ---------------------------------------------------------------------------
// Kernel 2a: per (chunk, bag) local top-10 / bottom-10. 1 wave per block.
// cand layout: [b][r][0..9 top desc, 10..19 bottom asc]
// ---------------------------------------------------------------------------
__global__ __launch_bounds__(64) void select1_kernel(
    const float* __restrict__ scores, float* __restrict__ cv, int* __restrict__ ci,
    int N, int CH)
{
    const int r = blockIdx.x, b = blockIdx.y;
    const int tid = threadIdx.x;
    const float* s = scores + (size_t)b * N;
    const int start = r * CH;
    const int end = min(N, start + CH);

    float tv[KSEL]; int ti[KSEL];
    float lv[KSEL]; int li[KSEL];
    #pragma unroll
    for (int j = 0; j < KSEL; ++j) { tv[j] = -FLT_MAX; ti[j] = -1; lv[j] = FLT_MAX; li[j] = -1; }

    for (int i = start + tid; i < end; i += 64) {
        float v = s[i];
        if (v > tv[KSEL-1]) {
            #pragma unroll
            for (int j = KSEL-1; j >= 1; --j) {
                if (v > tv[j-1])      { tv[j] = tv[j-1]; ti[j] = ti[j-1]; }
                else if (v > tv[j])   { tv[j] = v;       ti[j] = i;       }
            }
            if (v > tv[0]) { tv[0] = v; ti[0] = i; }
        }
        if (v < lv[KSEL-1]) {
            #pragma unroll
            for (int j = KSEL-1; j >= 1; --j) {
                if (v < lv[j-1])      { lv[j] = lv[j-1]; li[j] = li[j-1]; }
                else if (v < lv[j])   { lv[j] = v;       li[j] = i;       }
            }
            if (v < lv[0]) { lv[0] = v; li[0] = i; }
        }
    }

    size_t base = ((size_t)b * NSEL1 + r) * 2 * KSEL;
    for (int rd = 0; rd < KSEL; ++rd) {
        float v = tv[0]; int who = tid;
        #pragma unroll
        for (int off = 32; off > 0; off >>= 1) {
            float ov = __shfl_down(v, off, 64);
            int ow = __shfl_down(who, off, 64);
            if (ov > v) { v = ov; who = ow; }
        }
        int bwho = __shfl(who, 0, 64);
        if (tid == bwho) {
            cv[base + rd] = tv[0]; ci[base + rd] = ti[0];
            #pragma unroll
            for (int j = 0; j < KSEL-1; ++j) { tv[j] = tv[j+1]; ti[j] = ti[j+1]; }
            tv[KSEL-1] = -FLT_MAX;
        }
    }
    for (int rd = 0; rd < KSEL; ++rd) {
        float v = lv[0]; int who = tid;
        #pragma unroll
        for (int off = 32; off > 0; off >>= 1) {
            float ov = __shfl_down(v, off, 64);
            int ow = __shfl_down(who, off, 64);
            if (ov < v) { v = ov; who = ow; }
        }
        int bwho = __shfl(who, 0, 64);
        if (tid == bwho) {
            cv[base + KSEL + rd] = lv[0]; ci[base + KSEL + rd] = li[0];
            #pragma unroll
            for (int j = 0; j < KSEL-1; ++j) { lv[j] = lv[j+1]; li[j] = li[j+1]; }
            lv[KSEL-1] = FLT_MAX;
        }
    }
}

// ---------------------------------------------------------------------------
// Kernel 2b: per bag merge of 32x10 candidates each side, softmax, scatter.
// 1 wave per block.
// ---------------------------------------------------------------------------
__global__ __launch_bounds__(64) void select2_kernel(
    const float* __restrict__ cv, const int* __restrict__ ci,
    float* __restrict__ atten, int* __restrict__ sel_idx, float* __restrict__ sel_w, int N)
{
    const int b = blockIdx.x;
    const int tid = threadIdx.x;
    __shared__ float selv[2*KSEL]; __shared__ int seli[2*KSEL];

    float tv[KSEL]; int ti[KSEL];
    float lv[KSEL]; int li[KSEL];
    #pragma unroll
    for (int j = 0; j < KSEL; ++j) { tv[j] = -FLT_MAX; ti[j] = -1; lv[j] = FLT_MAX; li[j] = -1; }

    for (int c = tid; c < NSEL1 * KSEL; c += 64) {
        int rr = c / KSEL, jj = c % KSEL;
        size_t base = ((size_t)b * NSEL1 + rr) * 2 * KSEL;
        {
            float v = cv[base + jj]; int idx = ci[base + jj];
            if (v > tv[KSEL-1]) {
                #pragma unroll
                for (int j = KSEL-1; j >= 1; --j) {
                    if (v > tv[j-1])      { tv[j] = tv[j-1]; ti[j] = ti[j-1]; }
                    else if (v > tv[j])   { tv[j] = v;       ti[j] = idx;     }
                }
                if (v > tv[0]) { tv[0] = v; ti[0] = idx; }
            }
        }
        {
            float v = cv[base + KSEL + jj]; int idx = ci[base + KSEL + jj];
            if (v < lv[KSEL-1]) {
                #pragma unroll
                for (int j = KSEL-1; j >= 1; --j) {
                    if (v < lv[j-1])      { lv[j] = lv[j-1]; li[j] = li[j-1]; }
                    else if (v < lv[j])   { lv[j] = v;       li[j] = idx;     }
                }
                if (v < lv[0]) { lv[0] = v; li[0] = idx; }
            }
        }
    }

    for (int rd = 0; rd < KSEL; ++rd) {
        float v = tv[0]; int who = tid;
        #pragma unroll
        for (int off = 32; off > 0; off >>= 1) {
            float ov = __shfl_down(v, off, 64);
            int ow = __shfl_down(who, off, 64);
            if (ov > v) { v = ov; who = ow; }
        }
        int bwho = __shfl(who, 0, 64);
        if (tid == bwho) {
            selv[rd] = tv[0]; seli[rd] = ti[0];
            #pragma unroll
            for (int j = 0; j < KSEL-1; ++j) { tv[j] = tv[j+1]; ti[j] = ti[j+1]; }
            tv[KSEL-1] = -FLT_MAX;
        }
    }
    for (int rd = 0; rd < KSEL; ++rd) {
        float v = lv[0]; int who = tid;
        #pragma unroll
        for (int off = 32; off > 0; off >>= 1) {
            float ov = __shfl_down(v, off, 64);
            int ow = __shfl_down(who, off, 64);
            if (ov < v) { v = ov; who = ow; }
        }
        int bwho = __shfl(who, 0, 64);
        if (tid == bwho) {
            selv[KSEL + rd] = lv[0]; seli[KSEL + rd] = li[0];
            #pragma unroll
            for (int j = 0; j < KSEL-1; ++j) { lv[j] = lv[j+1]; li[j] = li[j+1]; }
            lv[KSEL-1] = FLT_MAX;
        }
    }
    __syncthreads();

    if (tid == 0) {
        float m = -FLT_MAX;
        #pragma unroll
        for (int j = 0; j < 2*KSEL; ++j) m = fmaxf(m, selv[j]);
        float e[2*KSEL]; float sum = 0.f;
        #pragma unroll
        for (int j = 0; j < 2*KSEL; ++j) { e[j] = expf(selv[j] - m); sum += e[j]; }
        float inv = 1.0f / sum;
        #pragma unroll
        for (int j = 0; j < 2*KSEL; ++j) {
            float w = e[j] * inv;
            atten[(size_t)b * N + seli[j]] = w;
            sel_idx[b * 2 * KSEL + j] = seli[j];
            sel_w[b * 2 * KSEL + j] = w;
        }
    }
}

// ---------------------------------------------------------------------------
// Kernel 3: Z[b,:] = sum_j w_j * x[b, idx_j, :]
// ---------------------------------------------------------------------------
__global__ __launch_bounds__(256) void z_kernel(
    const float* __restrict__ x, const int* __restrict__ sel_idx,
    const float* __restrict__ sel_w, float* __restrict__ Z, int N)
{
    const int b = blockIdx.x;
    const int tid = threadIdx.x;
    float4 acc = make_float4(0.f, 0.f, 0.f, 0.f);
    #pragma unroll
    for (int j = 0; j < 2*KSEL; ++j) {
        int idx = sel_idx[b * 2 * KSEL + j];
        float w = sel_w[b * 2 * KSEL + j];
        const float4* xr = (const float4*)(x + ((size_t)b * N + idx) * INPUT_DIM);
        float4 v = xr[tid];
        acc.x = fmaf(w, v.x, acc.x);
        acc.y = fmaf(w, v.y, acc.y);
        acc.z = fmaf(w, v.z, acc.z);
        acc.w = fmaf(w, v.w, acc.w);
    }
    ((float4*)(Z + (size_t)b * INPUT_DIM))[tid] = acc;
}

extern "C" void kernel_launch(void* const* d_in, const int* in_sizes, int n_in,
                              void* d_out, int out_size, void* d_ws, size_t ws_size,
                              hipStream_t stream)
{
    const float* x  = (const float*)d_in[0];
    const float* Wv = (const float*)d_in[1];
    const float* bv = (const float*)d_in[2];
    const float* Wu = (const float*)d_in[3];
    const float* bu = (const float*)d_in[4];
    const float* Ww = (const float*)d_in[5];
    const float* bw = (const float*)d_in[6];

    const int B = 8;
    const int N = in_sizes[0] / (B * INPUT_DIM);   // 50000

    float* Z = (float*)d_out;                              // [B,1024]
    float* atten = (float*)d_out + (size_t)B * INPUT_DIM;  // [B,N]

    // workspace layout
    char* p = (char*)d_ws;
    float* scores = (float*)p;                  p += (size_t)B * N * sizeof(float);
    unsigned short* wp_hi = (unsigned short*)p; p += (size_t)INPUT_DIM * 256 * sizeof(unsigned short);
    unsigned short* wp_lo = (unsigned short*)p; p += (size_t)INPUT_DIM * 256 * sizeof(unsigned short);
    float* cand_v = (float*)p;                  p += (size_t)B * NSEL1 * 2 * KSEL * sizeof(float);
    int* cand_i = (int*)p;                      p += (size_t)B * NSEL1 * 2 * KSEL * sizeof(int);
    int* sel_idx = (int*)p;                     p += (size_t)B * 2 * KSEL * sizeof(int);
    float* sel_w = (float*)p;

    repack_kernel<<<512, 64, 0, stream>>>(Wv, Wu, wp_hi, wp_lo);

    dim3 g1((N + BM - 1) / BM, B);
    scores_kernel<<<g1, STH, 0, stream>>>(x, wp_hi, wp_lo, bv, bu, Ww, bw, scores, atten, N);

    int CH = (N + NSEL1 - 1) / NSEL1;
    dim3 g2(NSEL1, B);
    select1_kernel<<<g2, 64, 0, stream>>>(scores, cand_v, cand_i, N, CH);
    select2_kernel<<<B, 64, 0, stream>>>(cand_v, cand_i, atten, sel_idx, sel_w, N);
    z_kernel<<<B, 256, 0, stream>>>(x, sel_idx, sel_w, Z, N);
}